// Round 11
// baseline (2168.565 us; speedup 1.0000x reference)
//
#include <hip/hip_runtime.h>
#include <string.h>

// LSTM_13159779795583 : 2-layer LSTM (B=32,T=512,IN=256,H=1024) + FC(1024->256)
//
// Round 11 = Round 10 + three targeted fixes (same arithmetic):
//  1. hh probe now samples one dword from EACH producer wave's 256B region
//     ((lane>>4)*256, was *8 == only wave 0's region) -> consumers no longer
//     first-touch payload lines before producer waves 1..3 have landed, which
//     was installing stale-NaN lines in consumer L2s and triggering chronic
//     coherent-redo fallbacks.
//  2. xw1 gets the same probe gate (was ungated first-touch).
//  3. L1 pipeline deepened by one iter: xw1 reads h0 slot i-2 (2 iters slack,
//     was 1) -> L1 can't catch up to the h0 production edge.
//     h1[t] = slot t+4, NITER=516, fc reads slot t+4.
//
// Protocol (R10-proven): NaN-prefilled write-once h slots; fire-and-forget 4B
// WT producer stores; consumers probe via sc0sc1 then read payload with plain
// cacheable loads validated inline; any NaN -> coherent redo. Correctness
// rests only on 4B store atomicity + NaN sentinel (G16-safe, placement-free).

#define T_STEPS 512
#define BATCH   32
#define IN_DIM  256
#define HID     1024
#define OUT_DIM 256
#define NWGL    64              // WGs per layer
#define TPB     512
#define U       16              // hidden units per WG
#define CHW     (BATCH * U)     // fp16 per chunk (512 = 1KB)
#define SLOTE   (NWGL * CHW)    // fp16 per slot (32768 = 64KB)
#define NITER   516             // i = 0..515

typedef _Float16 half8  __attribute__((ext_vector_type(8)));
typedef float    f32x16 __attribute__((ext_vector_type(16)));
typedef int      v4i    __attribute__((ext_vector_type(4)));

__device__ __forceinline__ float sigm(float x)      { return 1.f / (1.f + __expf(-x)); }
__device__ __forceinline__ float tanh_fast(float x) { return 2.f / (1.f + __expf(-2.f * x)) - 1.f; }

#define ATOMIC_ST4(p, v) __hip_atomic_store((p), (v), __ATOMIC_RELAXED, __HIP_MEMORY_SCOPE_AGENT)

// coherent 4B probe (bypass L1/L2); memory clobber = compiler barrier so the
// cacheable payload loads below cannot be hoisted above the gate
__device__ __forceinline__ unsigned probe4(const char* p) {
    unsigned v;
    asm volatile("global_load_dword %0, %1, off sc0 sc1\n\t"
                 "s_waitcnt vmcnt(0)" : "=v"(v) : "v"(p) : "memory");
    return v;
}

// 8 coherent 16B loads (chunk stride 1024B), one vmcnt(0)
__device__ __forceinline__ void ld8_coherent(const char* b0, v4i* F) {
    asm volatile(
        "global_load_dwordx4 %0, %8, off sc0 sc1\n\t"
        "global_load_dwordx4 %1, %8, off offset:1024 sc0 sc1\n\t"
        "global_load_dwordx4 %2, %8, off offset:2048 sc0 sc1\n\t"
        "global_load_dwordx4 %3, %8, off offset:3072 sc0 sc1\n\t"
        "global_load_dwordx4 %4, %9, off sc0 sc1\n\t"
        "global_load_dwordx4 %5, %9, off offset:1024 sc0 sc1\n\t"
        "global_load_dwordx4 %6, %9, off offset:2048 sc0 sc1\n\t"
        "global_load_dwordx4 %7, %9, off offset:3072 sc0 sc1\n\t"
        "s_waitcnt vmcnt(0)"
        : "=&v"(F[0]), "=&v"(F[1]), "=&v"(F[2]), "=&v"(F[3]),
          "=&v"(F[4]), "=&v"(F[5]), "=&v"(F[6]), "=&v"(F[7])
        : "v"(b0), "v"(b0 + 4096)
        : "memory");
}

// producers store 4B units; check low u16 of every dword
__device__ __forceinline__ bool frag_ok4(v4i f) {
    return ((f.x & 0xffff) != 0x7E7E) & ((f.y & 0xffff) != 0x7E7E)
         & ((f.z & 0xffff) != 0x7E7E) & ((f.w & 0xffff) != 0x7E7E);
}

__global__ __launch_bounds__(TPB, 2) void lstm_persist(
    const float* __restrict__ W_ih0, const float* __restrict__ W_hh0,
    const float* __restrict__ b_ih0, const float* __restrict__ b_hh0,
    const float* __restrict__ W_ih1, const float* __restrict__ W_hh1,
    const float* __restrict__ b_ih1, const float* __restrict__ b_hh1,
    const _Float16* __restrict__ xb,
    _Float16* __restrict__ h0a, _Float16* __restrict__ h1a)
{
    __shared__ float stage[2][8][BATCH][65];  // [buf][wave][b][n 0..63 +pad]
    __shared__ float cst[BATCH][17];          // cell state (padded; 16 used)
    __shared__ float biasS[64];               // b_ih+b_hh, 64 gate rows

    const int tid  = threadIdx.x;
    const int w    = tid >> 6;
    const int lane = tid & 63;
    const int rho  = lane & 31;
    const int kg   = (lane >> 5) << 3;   // 0 or 8
    const int blk  = blockIdx.x;
    const int isL1 = blk >= NWGL;
    const int be   = blk & (NWGL - 1);
    const bool isHH = (w < 4);

    const float* wptr; int kbase, nf, rowlen;
    if (isHH)      { wptr = isL1 ? W_hh1 : W_hh0; kbase = w * 256;       nf = 16; rowlen = HID;    }
    else if (isL1) { wptr = W_ih1;                kbase = (w - 4) * 256; nf = 16; rowlen = HID;    }
    else           { wptr = W_ih0;                kbase = (w - 4) * 64;  nf = 4;  rowlen = IN_DIM; }

    // ---- B fragments (fp32 -> fp16), once. Bf[kf][nh], nn = nh*32+rho ----
    half8 Bf[16][2];
    #pragma unroll
    for (int kf = 0; kf < 16; ++kf)
        #pragma unroll
        for (int nh = 0; nh < 2; ++nh) {
            half8 bf;
            if (kf < nf) {
                const int nn = nh * 32 + rho;
                const int row = (nn >> 4) * HID + be * U + (nn & 15);
                const float* p = wptr + (size_t)row * rowlen + kbase + kf * 16 + kg;
                float4 lo = *(const float4*)p;
                float4 hi = *(const float4*)(p + 4);
                bf[0] = (_Float16)lo.x; bf[1] = (_Float16)lo.y;
                bf[2] = (_Float16)lo.z; bf[3] = (_Float16)lo.w;
                bf[4] = (_Float16)hi.x; bf[5] = (_Float16)hi.y;
                bf[6] = (_Float16)hi.z; bf[7] = (_Float16)hi.w;
            } else {
                #pragma unroll
                for (int j = 0; j < 8; ++j) bf[j] = (_Float16)0.f;
            }
            Bf[kf][nh] = bf;
        }

    // ---- init ----
    if (tid < 64) {
        const int row = (tid >> 4) * HID + be * U + (tid & 15);
        biasS[tid] = isL1 ? (b_ih1[row] + b_hh1[row]) : (b_ih0[row] + b_hh0[row]);
    }
    if (tid < 512) cst[tid >> 4][tid & 15] = 0.f;
    __syncthreads();

    _Float16* hout = isL1 ? h1a : h0a;
    const _Float16* hself = hout;

    // ---- cell at head: compute h for slot, fire-and-forget WT store ----
    auto docell = [&](int slot, int sbp) {
        const int cid = w * 128 + lane * 2;
        const int b = cid >> 4, u0 = cid & 15;
        _Float16 h2[2];
        #pragma unroll
        for (int j = 0; j < 2; ++j) {
            const int u = u0 + j;
            float pre[4];
            #pragma unroll
            for (int g = 0; g < 4; ++g) {
                const int n = g * 16 + u;
                float v = biasS[n];
                #pragma unroll
                for (int p = 0; p < 8; ++p) v += stage[sbp][p][b][n];
                pre[g] = v;
            }
            float iv = sigm(pre[0]);
            float fv = sigm(pre[1]);
            float gv = tanh_fast(pre[2]);
            float ov = sigm(pre[3]);
            float c  = fv * cst[b][u] + iv * gv;
            cst[b][u] = c;
            h2[j] = (_Float16)(ov * tanh_fast(c));
        }
        unsigned pk; memcpy(&pk, h2, 4);
        ATOMIC_ST4((unsigned*)(hout + (size_t)slot * SLOTE + be * CHW + b * U + u0), pk);
    };

    #pragma unroll 1
    for (int i = 0; i < NITER; ++i) {
        const int sb = i & 1;

        const bool cell_act = isL1 ? (i >= 4 && i <= 515) : (i >= 1 && i <= 512);
        if (isHH && cell_act) docell(i, (i - 1) & 1);

        const bool comp_act = isL1 ? (i >= 3 && i < 3 + T_STEPS) : (i < T_STEPS);
        if (comp_act) {
            f32x16 acc0, acc1;
            #pragma unroll
            for (int r = 0; r < 16; ++r) { acc0[r] = 0.f; acc1[r] = 0.f; }

            if (isHH || isL1) {
                // payload base: hh reads own layer slot i; xw1 reads h0 slot i-2
                const _Float16* slotb;
                const int cw = isHH ? w : (w - 4);
                if (isHH) slotb = hself + (size_t)i * SLOTE;
                else      slotb = h0a + (size_t)(i - 2) * SLOTE;

                // probe gate: 16 chunks x one dword from EACH producer wave's
                // 256B region ((lane>>4)*256) -> no early first-touch
                {
                    const char* pp = (const char*)slotb
                        + (size_t)(cw * 16 + (lane & 15)) * 1024
                        + (size_t)(lane >> 4) * 256;
                    while (!__all((probe4(pp) & 0xffffu) != 0x7E7Eu)) {}
                }

                const _Float16* ap = slotb + (size_t)(cw * 16) * CHW + rho * U + kg;
                // fast path: cacheable loads, validate inline while MFMA-ing
                bool ok = true;
                #pragma unroll
                for (int j = 0; j < 16; ++j) {
                    v4i f = *(const v4i*)(ap + (size_t)j * CHW);
                    ok &= frag_ok4(f);
                    half8 a = __builtin_bit_cast(half8, f);
                    acc0 = __builtin_amdgcn_mfma_f32_32x32x16_f16(a, Bf[j][0], acc0, 0, 0, 0);
                    acc1 = __builtin_amdgcn_mfma_f32_32x32x16_f16(a, Bf[j][1], acc1, 0, 0, 0);
                }
                if (!__all(ok)) {
                    // rare straggler: discard and redo coherently (R7-proven)
                    #pragma unroll
                    for (int r = 0; r < 16; ++r) { acc0[r] = 0.f; acc1[r] = 0.f; }
                    #pragma unroll
                    for (int g = 0; g < 2; ++g) {
                        v4i F[8];
                        for (;;) {
                            ld8_coherent((const char*)(ap + (size_t)g * 8 * CHW), F);
                            bool ok2 = true;
                            #pragma unroll
                            for (int j = 0; j < 8; ++j) ok2 &= frag_ok4(F[j]);
                            if (__all(ok2)) break;
                            __builtin_amdgcn_s_sleep(1);
                        }
                        #pragma unroll
                        for (int j = 0; j < 8; ++j) {
                            half8 a = __builtin_bit_cast(half8, F[j]);
                            acc0 = __builtin_amdgcn_mfma_f32_32x32x16_f16(a, Bf[g * 8 + j][0], acc0, 0, 0, 0);
                            acc1 = __builtin_amdgcn_mfma_f32_32x32x16_f16(a, Bf[g * 8 + j][1], acc1, 0, 0, 0);
                        }
                    }
                }
            } else {
                // xw0: static x, 4 frags
                const _Float16* ap = xb + ((size_t)i * 16 + (w - 4) * 4) * CHW + rho * U + kg;
                #pragma unroll
                for (int j = 0; j < 4; ++j) {
                    half8 a = *(const half8*)(ap + (size_t)j * CHW);
                    acc0 = __builtin_amdgcn_mfma_f32_32x32x16_f16(a, Bf[j][0], acc0, 0, 0, 0);
                    acc1 = __builtin_amdgcn_mfma_f32_32x32x16_f16(a, Bf[j][1], acc1, 0, 0, 0);
                }
            }
            // C/D: n = lane&31, b = (r&3)+8*(r>>2)+4*(lane>>5)
            #pragma unroll
            for (int r = 0; r < 16; ++r) {
                const int b = (r & 3) + ((r >> 2) << 3) + ((lane >> 5) << 2);
                stage[sb][w][b][rho]      = acc0[r];
                stage[sb][w][b][32 + rho] = acc1[r];
            }
        }
        __syncthreads();
    }
}

// ---- epilogue FC: h1[t] = slot t+4, layout [slot][wg][b][u16] ----
__global__ __launch_bounds__(256) void fc_kern(
    const _Float16* __restrict__ h1a, const _Float16* __restrict__ fcwb,
    const float* __restrict__ fc_b, float* __restrict__ out)
{
    const int wv   = threadIdx.x >> 6;
    const int lane = threadIdx.x & 63;
    const int t    = blockIdx.x * 4 + wv;
    const int kg   = (lane >> 5) << 3;
    const _Float16* ab = h1a + (size_t)(t + 4) * SLOTE + (size_t)(lane & 31) * U + kg;

    #pragma unroll 1
    for (int nt = 0; nt < 8; ++nt) {
        const _Float16* bb = fcwb + (size_t)(nt * 32 + (lane & 31)) * HID + kg;
        f32x16 acc0, acc1;
        #pragma unroll
        for (int r = 0; r < 16; ++r) { acc0[r] = 0.f; acc1[r] = 0.f; }
        #pragma unroll
        for (int kk = 0; kk < 64; kk += 2) {
            half8 a0 = *(const half8*)(ab + (size_t)kk * CHW);
            half8 b0 = *(const half8*)(bb + kk * 16);
            acc0 = __builtin_amdgcn_mfma_f32_32x32x16_f16(a0, b0, acc0, 0, 0, 0);
            half8 a1 = *(const half8*)(ab + (size_t)(kk + 1) * CHW);
            half8 b1 = *(const half8*)(bb + (kk + 1) * 16);
            acc1 = __builtin_amdgcn_mfma_f32_32x32x16_f16(a1, b1, acc1, 0, 0, 0);
        }
        const int o = nt * 32 + (lane & 31);
        const float bias = fc_b[o];
        #pragma unroll
        for (int r = 0; r < 16; ++r) {
            const int m = (r & 3) + ((r >> 2) << 3) + ((lane >> 5) << 2);
            out[(size_t)m * (T_STEPS * OUT_DIM) + (size_t)t * OUT_DIM + o]
                = acc0[r] + acc1[r] + bias;
        }
    }
}

// ---- pre-cast x (-> [t][chunk16][b][16] fp16) and fc_w (-> fp16) ----
__global__ __launch_bounds__(256) void precast(
    const float* __restrict__ x, const float* __restrict__ fcw,
    _Float16* __restrict__ xb, _Float16* __restrict__ fcwb)
{
    const int idx = blockIdx.x * 256 + threadIdx.x;
    const int N1 = T_STEPS * BATCH * IN_DIM / 4;
    const int N2 = OUT_DIM * HID / 4;
    if (idx < N1) {
        int e = idx << 2;
        int d = e & (IN_DIM - 1);
        int bt = e >> 8;
        int b = bt & 31;
        int t = bt >> 5;
        float4 v = *(const float4*)(x + ((size_t)b * T_STEPS + t) * IN_DIM + d);
        _Float16* dst = xb + (((size_t)t * 16 + (d >> 4)) * 32 + b) * 16 + (d & 15);
        dst[0] = (_Float16)v.x; dst[1] = (_Float16)v.y;
        dst[2] = (_Float16)v.z; dst[3] = (_Float16)v.w;
    } else if (idx < N1 + N2) {
        int e = (idx - N1) << 2;
        float4 v = *(const float4*)(fcw + e);
        _Float16* dst = fcwb + e;
        dst[0] = (_Float16)v.x; dst[1] = (_Float16)v.y;
        dst[2] = (_Float16)v.z; dst[3] = (_Float16)v.w;
    }
}

extern "C" void kernel_launch(void* const* d_in, const int* in_sizes, int n_in,
                              void* d_out, int out_size, void* d_ws, size_t ws_size,
                              hipStream_t stream) {
    const float* x     = (const float*)d_in[0];
    const float* W_ih0 = (const float*)d_in[1];
    const float* W_hh0 = (const float*)d_in[2];
    const float* b_ih0 = (const float*)d_in[3];
    const float* b_hh0 = (const float*)d_in[4];
    const float* W_ih1 = (const float*)d_in[5];
    const float* W_hh1 = (const float*)d_in[6];
    const float* b_ih1 = (const float*)d_in[7];
    const float* b_hh1 = (const float*)d_in[8];
    const float* fc_w  = (const float*)d_in[9];
    const float* fc_b  = (const float*)d_in[10];
    float* out = (float*)d_out;

    char* ws = (char*)d_ws;
    size_t off = 0;
    _Float16* xb   = (_Float16*)(ws + off); off += (size_t)T_STEPS * BATCH * IN_DIM * 2;
    _Float16* h0a  = (_Float16*)(ws + off); off += (size_t)513 * SLOTE * 2;
    _Float16* h1a  = (_Float16*)(ws + off); off += (size_t)516 * SLOTE * 2;
    _Float16* fcwb = (_Float16*)(ws + off); off += (size_t)OUT_DIM * HID * 2;
    // total ws use ~74.6 MB

    // NaN-sentinel prefill, then zero the initial-state slots
    hipMemsetAsync(h0a, 0x7E, (size_t)513 * SLOTE * 2, stream);
    hipMemsetAsync(h1a, 0x7E, (size_t)516 * SLOTE * 2, stream);
    hipMemsetAsync(h0a, 0, (size_t)SLOTE * 2, stream);                      // h0 slot 0
    hipMemsetAsync(h1a + (size_t)3 * SLOTE, 0, (size_t)SLOTE * 2, stream);  // h1 slot 3
    precast<<<4352, 256, 0, stream>>>(x, fc_w, xb, fcwb);
    lstm_persist<<<128, TPB, 0, stream>>>(W_ih0, W_hh0, b_ih0, b_hh0,
                                          W_ih1, W_hh1, b_ih1, b_hh1,
                                          xb, h0a, h1a);
    fc_kern<<<128, 256, 0, stream>>>(h1a, fcwb, fc_b, out);
}